// Round 16
// baseline (47.102 us; speedup 1.0000x reference)
//
#include <hip/hip_runtime.h>
#include <hip/hip_fp16.h>

#define NN 1536      // n_nodes
#define FDIM 32      // p == fts == 32
#define TG 96        // tile (grid 16x16 = 256 blocks = 1/CU, 8 waves each)
#define KS 64        // i8 K-step per half (64 B per row)
#define NTH 12       // K-steps per half (768/64)

typedef __attribute__((ext_vector_type(4))) int i32x4;
typedef __attribute__((ext_vector_type(4))) float f32x4;
typedef _Float16 h16x2 __attribute__((ext_vector_type(2)));

typedef __attribute__((address_space(3))) unsigned char as3_u8;
typedef __attribute__((address_space(1))) unsigned char as1_u8;

__device__ __forceinline__ void gload_lds16(const void* g, void* l) {
    __builtin_amdgcn_global_load_lds((const as1_u8*)g, (as3_u8*)l, 16, 0, 0);
}

// ---------------------------------------------------------------------------
// absmax(A): 256 blocks grid-stride, wave shuffle-reduce, LDS cross-wave,
// ONE atomic per block (r6-verified).
// ---------------------------------------------------------------------------
__global__ __launch_bounds__(256) void gud_absmax(const float* __restrict__ A,
                                                  unsigned* __restrict__ amax) {
    __shared__ float red[4];
    const float4* A4 = reinterpret_cast<const float4*>(A);
    float m = 0.f;
    for (int idx = blockIdx.x * 256 + threadIdx.x; idx < NN * NN / 4;
         idx += 256 * 256) {
        float4 v = A4[idx];
        m = fmaxf(m, fmaxf(fmaxf(fabsf(v.x), fabsf(v.y)),
                           fmaxf(fabsf(v.z), fabsf(v.w))));
    }
#pragma unroll
    for (int k = 32; k >= 1; k >>= 1)
        m = fmaxf(m, __shfl_xor(m, k, 64));
    if ((threadIdx.x & 63) == 0) red[threadIdx.x >> 6] = m;
    __syncthreads();
    if (threadIdx.x == 0) {
        m = fmaxf(fmaxf(red[0], red[1]), fmaxf(red[2], red[3]));
        atomicMax(amax, __float_as_uint(m));
    }
}

// ---------------------------------------------------------------------------
// Fused quant (A -> i8 H/L, 15-bit fixed point) + prep (f16 QI/RJ).
// ---------------------------------------------------------------------------
__global__ __launch_bounds__(256) void gud_quantprep(
        const float* __restrict__ A,
        const unsigned* __restrict__ amaxu,
        unsigned char* __restrict__ qH,
        unsigned char* __restrict__ qL,
        const float* __restrict__ P,
        const float* __restrict__ W1,
        const float* __restrict__ b1,
        _Float16* __restrict__ QIh,
        _Float16* __restrict__ RJh) {
    const int b = blockIdx.x;
    if (b < NN * NN / 1024) {
        const float inv = 32639.0f / __uint_as_float(*amaxu);
        int gid = b * 256 + threadIdx.x;
        float4 v = reinterpret_cast<const float4*>(A)[gid];
        unsigned hw = 0, lw = 0;
        float elems[4] = {v.x, v.y, v.z, v.w};
#pragma unroll
        for (int e = 0; e < 4; ++e) {
            int q  = (int)rintf(fminf(fmaxf(elems[e] * inv, -32639.f), 32639.f));
            int hh = (q + 128) >> 8;           // floor((q+128)/256)
            int ll = q - (hh << 8);            // in [-128,127]
            hw |= ((unsigned)(hh & 0xff)) << (8 * e);
            lw |= ((unsigned)(ll & 0xff)) << (8 * e);
        }
        reinterpret_cast<unsigned*>(qH)[gid] = hw;
        reinterpret_cast<unsigned*>(qL)[gid] = lw;
    } else {
        int gid = (b - NN * NN / 1024) * 256 + threadIdx.x;   // 0 .. NN*64-1
        int i  = gid >> 6;
        int lf = gid & 63;
        int l  = (lf >> 5) + 1;   // 1 or 2
        int f  = lf & 31;
        const float* prow = P + i * FDIM;
        const float* wp   = W1 + l * FDIM * FDIM + f;
        float q = 0.f;
#pragma unroll
        for (int c = 0; c < FDIM; ++c) q = fmaf(prow[c], wp[c * FDIM], q);
        QIh[i * 64 + lf] = (_Float16)(q + b1[l * FDIM + f]);
        RJh[i * 64 + lf] = (_Float16)(-q);
    }
}

// ---------------------------------------------------------------------------
// Fused i8 GEMM + conv (r15 structure) with THREE LEXICALLY DISTINCT LDS
// buffers + fully unrolled 12-step K-loop: alias analysis can now prove the
// ds_reads of the compute buffer don't alias outstanding global_load_lds
// writes to the other two, so the compiler cannot insert a vmcnt(0) drain —
// only our counted vmcnt(6) remains (vmcnt(0) at the final step only).
// ---------------------------------------------------------------------------
__global__ __launch_bounds__(512, 1) void gud_fused(
        const unsigned char* __restrict__ qH,
        const unsigned char* __restrict__ qL,
        const unsigned* __restrict__ amaxu,
        const float* __restrict__ A,
        const _Float16* __restrict__ QIh,
        const _Float16* __restrict__ RJh,
        const float* __restrict__ b1,
        const float* __restrict__ W2,
        const float* __restrict__ b2,
        float* __restrict__ out) {
    __shared__ alignas(16) char sb0[49152];
    __shared__ alignas(16) char sb1[49152];
    __shared__ alignas(16) char sb2[49152];

    const int tid  = threadIdx.x;
    const int lane = tid & 63;
    const int w    = tid >> 6;          // wave 0..7
    const int kh   = w >> 2;            // K-half
    const int sub  = w & 3;             // 0=H@i0, 1=L@i0, 2=H@j0, 3=L@j0
    const int wr   = sub >> 1, wc = sub & 1;

    // XCD-chunked swizzle over the 256-block grid (256 % 8 == 0)
    const int lin = blockIdx.x;
    const int swz = (lin & 7) * 32 + (lin >> 3);
    const int by  = swz >> 4, bx = swz & 15;
    const int i0  = by * TG, j0 = bx * TG;

    // ---- staging: wave w owns subtile (kh, sub) of each buffer
    const unsigned char* src = (sub & 1) ? qL : qH;
    const int rowbase = (sub < 2) ? i0 : j0;
    const int khbyte  = kh * (NN / 2);  // kh * 768 cols * 1 B
    int goffs[6];
#pragma unroll
    for (int s = 0; s < 6; ++s) {
        int rt    = 16 * s + (lane >> 2);          // row within tile 0..95
        int chunk = (lane & 3) ^ ((rt >> 1) & 3);  // inverse swizzle on source
        goffs[s]  = (rowbase + rt) * NN + khbyte + chunk * 16;
    }

    // ---- fragment read offsets (within this half's region of a buffer)
    const int hbase = kh * 24576;
    int aoff[3], boff[3];
    const int kb = lane >> 4;
#pragma unroll
    for (int m = 0; m < 3; ++m) {
        int ra  = wr * 48 + m * 16 + (lane & 15);
        aoff[m] = hbase + ra * 64 + ((kb ^ ((ra >> 1) & 3)) * 16);
        int rb  = wc * 48 + m * 16 + (lane & 15);
        boff[m] = hbase + 12288 + rb * 64 + ((kb ^ ((rb >> 1) & 3)) * 16);
    }

    i32x4 accH[3][3], accX[3][3];
#pragma unroll
    for (int m = 0; m < 3; ++m)
#pragma unroll
        for (int n = 0; n < 3; ++n) {
            accH[m][n] = (i32x4){0, 0, 0, 0};
            accX[m][n] = (i32x4){0, 0, 0, 0};
        }

    auto compute = [&](const char (&buf)[49152]) {
        i32x4 hA[3], lA[3], hB[3], lB[3];
#pragma unroll
        for (int m = 0; m < 3; ++m) {
            hA[m] = *(const i32x4*)(&buf[aoff[m]]);
            lA[m] = *(const i32x4*)(&buf[aoff[m] + 6144]);
            hB[m] = *(const i32x4*)(&buf[boff[m]]);
            lB[m] = *(const i32x4*)(&buf[boff[m] + 6144]);
        }
#pragma unroll
        for (int m = 0; m < 3; ++m)
#pragma unroll
            for (int n = 0; n < 3; ++n) {
                accH[m][n] = __builtin_amdgcn_mfma_i32_16x16x64_i8(hA[m], hB[n], accH[m][n], 0, 0, 0);
                accX[m][n] = __builtin_amdgcn_mfma_i32_16x16x64_i8(hA[m], lB[n], accX[m][n], 0, 0, 0);
                accX[m][n] = __builtin_amdgcn_mfma_i32_16x16x64_i8(lA[m], hB[n], accX[m][n], 0, 0, 0);
            }
    };

    // ---- prologue: stage tile 0 -> sb0, tile 1 -> sb1
#pragma unroll
    for (int s = 0; s < 6; ++s)
        gload_lds16((const char*)src + goffs[s], sb0 + w * 6144 + s * 1024);
#pragma unroll
    for (int s = 0; s < 6; ++s)
        gload_lds16((const char*)src + goffs[s] + KS, sb1 + w * 6144 + s * 1024);

    // ---- fully unrolled main loop: static buffer names, counted vmcnt.
    // Wait-BEFORE-barrier publishes each wave's staged tile to its kh group.
#define GSTEP(BC, BS, KT, VC) do {                                           \
    asm volatile("s_waitcnt vmcnt(" #VC ")" ::: "memory");                   \
    __builtin_amdgcn_s_barrier();                                            \
    if ((KT) < NTH) {                                                        \
        _Pragma("unroll")                                                    \
        for (int s = 0; s < 6; ++s)                                          \
            gload_lds16((const char*)src + goffs[s] + (KT) * KS,             \
                        BS + w * 6144 + s * 1024);                           \
    }                                                                        \
    compute(BC);                                                             \
} while (0)

    GSTEP(sb0, sb2, 2, 6);    // kt=0
    GSTEP(sb1, sb0, 3, 6);    // kt=1
    GSTEP(sb2, sb1, 4, 6);    // kt=2
    GSTEP(sb0, sb2, 5, 6);    // kt=3
    GSTEP(sb1, sb0, 6, 6);    // kt=4
    GSTEP(sb2, sb1, 7, 6);    // kt=5
    GSTEP(sb0, sb2, 8, 6);    // kt=6
    GSTEP(sb1, sb0, 9, 6);    // kt=7
    GSTEP(sb2, sb1, 10, 6);   // kt=8
    GSTEP(sb0, sb2, 11, 6);   // kt=9
    GSTEP(sb1, sb0, 12, 6);   // kt=10 (no stage)
    GSTEP(sb2, sb1, 13, 0);   // kt=11 (no stage, full drain)
#undef GSTEP

    // ---- dequant to f32 (accH/accX die here; frees VGPRs for epilogue)
    const float sq = __uint_as_float(*amaxu) / 32639.0f;
    const float c1 = sq * sq * 65536.0f;
    const float c2 = sq * sq * 256.0f;
    f32x4 af[3][3];
#pragma unroll
    for (int m = 0; m < 3; ++m)
#pragma unroll
        for (int n = 0; n < 3; ++n)
#pragma unroll
            for (int r = 0; r < 4; ++r)
                af[m][n][r] = c1 * (float)accH[m][n][r] + c2 * (float)accX[m][n][r];

    // ---- a2 exchange (kh=1 -> sb1) + QI/RJ staging (-> sb0)
    if (kh == 1) {
        char* pbase = sb1 + sub * 9216 + lane * 144;
#pragma unroll
        for (int m = 0; m < 3; ++m)
#pragma unroll
            for (int n = 0; n < 3; ++n)
                *(f32x4*)(pbase + (m * 3 + n) * 16) = af[m][n];
    }
    if (w < 4) {        // QI: 96 rows x 128 B -> sb0[0..12288)
#pragma unroll
        for (int sl = 0; sl < 3; ++sl) {
            int base = (w * 3 + sl) * 64;
            int idx  = base + lane;
            int c    = idx / 96;
            int row  = idx - c * 96;
            gload_lds16(QIh + (size_t)(i0 + row) * 64 + c * 8, sb0 + base * 16);
        }
    } else {            // RJ -> sb0[12288..24576)
#pragma unroll
        for (int sl = 0; sl < 3; ++sl) {
            int base = ((w - 4) * 3 + sl) * 64;
            int idx  = base + lane;
            int c    = idx / 96;
            int row  = idx - c * 96;
            gload_lds16(RJh + (size_t)(j0 + row) * 64 + c * 8, sb0 + 12288 + base * 16);
        }
    }

    // epilogue geometry + early A loads (kh=0 only; latency hides under sync)
    const int crow = (lane >> 4) * 4;
    const int ccol = lane & 15;
    int il[3], jl[3];
#pragma unroll
    for (int m = 0; m < 3; ++m) il[m] = wr * 48 + m * 16 + crow;
#pragma unroll
    for (int n = 0; n < 3; ++n) jl[n] = wc * 48 + n * 16 + ccol;

    float av[3][3][4];
    if (kh == 0) {
#pragma unroll
        for (int m = 0; m < 3; ++m)
#pragma unroll
            for (int n = 0; n < 3; ++n)
#pragma unroll
                for (int r = 0; r < 4; ++r)
                    av[m][n][r] = A[(size_t)(i0 + il[m] + r) * NN + j0 + jl[n]];
    }

    __syncthreads();    // drains vmcnt (QI/RJ, A) + lgkm (a2 ds_writes)

    if (kh == 1) return;

    // ---- add partner half's a2
    {
        const char* pbase = sb1 + sub * 9216 + lane * 144;
#pragma unroll
        for (int m = 0; m < 3; ++m)
#pragma unroll
            for (int n = 0; n < 3; ++n)
                af[m][n] += *(const f32x4*)(pbase + (m * 3 + n) * 16);
    }

    // ---- conv epilogue (f16 dot2, two-pass; r7/r13-verified)
    const char* QIl = sb0;
    const char* RJl = sb0 + 12288;

    float c0 = b2[0];
#pragma unroll
    for (int f = 0; f < FDIM; ++f) c0 = fmaf(fmaxf(b1[f], 0.f), W2[f], c0);
    const float bb1 = b2[1], bb2 = b2[2];

    h16x2 w2h[32];
#pragma unroll
    for (int k = 0; k < 32; ++k) {
        h16x2 t; t.x = (_Float16)W2[32 + 2 * k]; t.y = (_Float16)W2[33 + 2 * k];
        w2h[k] = t;
    }

    float mm[3][3][4];
    // pass 1: chunks 0..3 (features 0..31, layer 1) -> m1, fold into av
#pragma unroll
    for (int m = 0; m < 3; ++m)
#pragma unroll
        for (int n = 0; n < 3; ++n)
#pragma unroll
            for (int r = 0; r < 4; ++r) mm[m][n][r] = 0.f;
#pragma unroll
    for (int c = 0; c < 4; ++c) {
        uint4 rv[3];
#pragma unroll
        for (int n = 0; n < 3; ++n)
            rv[n] = *(const uint4*)(RJl + (c * 96 + jl[n]) * 16);
        uint4 qv[3][4];
#pragma unroll
        for (int m = 0; m < 3; ++m)
#pragma unroll
            for (int r = 0; r < 4; ++r)
                qv[m][r] = *(const uint4*)(QIl + (c * 96 + il[m] + r) * 16);
#pragma unroll
        for (int m = 0; m < 3; ++m)
#pragma unroll
            for (int n = 0; n < 3; ++n) {
                const unsigned* ru = (const unsigned*)&rv[n];
#pragma unroll
                for (int r = 0; r < 4; ++r) {
                    const unsigned* qu = (const unsigned*)&qv[m][r];
                    float acc_f = mm[m][n][r];
#pragma unroll
                    for (int e = 0; e < 4; ++e) {
                        h16x2 q = __builtin_bit_cast(h16x2, qu[e]);
                        h16x2 j = __builtin_bit_cast(h16x2, ru[e]);
                        h16x2 h = q + j;
                        h16x2 z = {(_Float16)0, (_Float16)0};
                        h = __builtin_elementwise_max(h, z);
                        acc_f = __builtin_amdgcn_fdot2(h, w2h[c * 4 + e], acc_f, false);
                    }
                    mm[m][n][r] = acc_f;
                }
            }
    }
#pragma unroll
    for (int m = 0; m < 3; ++m)
#pragma unroll
        for (int n = 0; n < 3; ++n)
#pragma unroll
            for (int r = 0; r < 4; ++r)
                av[m][n][r] *= (mm[m][n][r] + bb1);

    // pass 2: chunks 4..7 (features 32..63, layer 2) -> m2
#pragma unroll
    for (int m = 0; m < 3; ++m)
#pragma unroll
        for (int n = 0; n < 3; ++n)
#pragma unroll
            for (int r = 0; r < 4; ++r) mm[m][n][r] = 0.f;
#pragma unroll
    for (int c = 4; c < 8; ++c) {
        uint4 rv[3];
#pragma unroll
        for (int n = 0; n < 3; ++n)
            rv[n] = *(const uint4*)(RJl + (c * 96 + jl[n]) * 16);
        uint4 qv[3][4];
#pragma unroll
        for (int m = 0; m < 3; ++m)
#pragma unroll
            for (int r = 0; r < 4; ++r)
                qv[m][r] = *(const uint4*)(QIl + (c * 96 + il[m] + r) * 16);
#pragma unroll
        for (int m = 0; m < 3; ++m)
#pragma unroll
            for (int n = 0; n < 3; ++n) {
                const unsigned* ru = (const unsigned*)&rv[n];
#pragma unroll
                for (int r = 0; r < 4; ++r) {
                    const unsigned* qu = (const unsigned*)&qv[m][r];
                    float acc_f = mm[m][n][r];
#pragma unroll
                    for (int e = 0; e < 4; ++e) {
                        h16x2 q = __builtin_bit_cast(h16x2, qu[e]);
                        h16x2 j = __builtin_bit_cast(h16x2, ru[e]);
                        h16x2 h = q + j;
                        h16x2 z = {(_Float16)0, (_Float16)0};
                        h = __builtin_elementwise_max(h, z);
                        acc_f = __builtin_amdgcn_fdot2(h, w2h[c * 4 + e], acc_f, false);
                    }
                    mm[m][n][r] = acc_f;
                }
            }
    }

    // final: out = A*(m1+bb1) + A2*(m2+bb2) + diag(c0)
#pragma unroll
    for (int m = 0; m < 3; ++m)
#pragma unroll
        for (int n = 0; n < 3; ++n)
#pragma unroll
            for (int r = 0; r < 4; ++r) {
                float v = av[m][n][r] + af[m][n][r] * (mm[m][n][r] + bb2);
                int gi = i0 + il[m] + r;
                int gj = j0 + jl[n];
                if (gi == gj) v += c0;
                out[(size_t)gi * NN + gj] = v;
            }
}

// ---------------------------------------------------------------------------
extern "C" void kernel_launch(void* const* d_in, const int* in_sizes, int n_in,
                              void* d_out, int out_size, void* d_ws, size_t ws_size,
                              hipStream_t stream) {
    const float* A  = (const float*)d_in[0];   // [NN,NN] A_norm (symmetric)
    const float* P  = (const float*)d_in[1];   // [NN,32]
    const float* W1 = (const float*)d_in[2];   // [3,32,32]
    const float* b1 = (const float*)d_in[3];   // [3,32]
    const float* W2 = (const float*)d_in[4];   // [3,32,1]
    const float* b2 = (const float*)d_in[5];   // [3,1]
    float* out = (float*)d_out;

    unsigned char* qH = (unsigned char*)d_ws;                    // NN*NN i8
    unsigned char* qL = qH + (size_t)NN * NN;                    // NN*NN i8
    _Float16* QIh = (_Float16*)(qL + (size_t)NN * NN);           // NN*64 f16
    _Float16* RJh = QIh + (size_t)NN * 64;                       // NN*64 f16
    unsigned* amax = (unsigned*)(RJh + (size_t)NN * 64);         // 1 u32

    hipMemsetAsync(amax, 0, 4, stream);
    gud_absmax<<<dim3(256), 256, 0, stream>>>(A, amax);
    gud_quantprep<<<dim3(NN * NN / 1024 + NN * 64 / 256), 256, 0, stream>>>(
        A, amax, qH, qL, P, W1, b1, QIh, RJh);
    gud_fused<<<dim3((NN / TG) * (NN / TG)), 512, 0, stream>>>(
        qH, qL, amax, A, QIh, RJh, b1, W2, b2, out);
}

// Round 17
// 42.156 us; speedup vs baseline: 1.1173x; 1.1173x over previous
//
#include <hip/hip_runtime.h>
#include <hip/hip_fp16.h>

#define NN 1536      // n_nodes
#define FDIM 32      // p == fts == 32
#define TG 96        // tile (grid 16x16 = 256 blocks = 1/CU, 8 waves each)
#define KS 64        // i8 K-step per half (64 B per row)
#define NTH 12       // K-steps per half (768/64)
#define NPMAX 768    // partial-max count (= absmax grid)

typedef __attribute__((ext_vector_type(4))) int i32x4;
typedef __attribute__((ext_vector_type(4))) float f32x4;
typedef _Float16 h16x2 __attribute__((ext_vector_type(2)));

typedef __attribute__((address_space(3))) unsigned char as3_u8;
typedef __attribute__((address_space(1))) unsigned char as1_u8;

__device__ __forceinline__ void gload_lds16(const void* g, void* l) {
    __builtin_amdgcn_global_load_lds((const as1_u8*)g, (as3_u8*)l, 16, 0, 0);
}

// Wave-local reduction of the 768 partial maxes (12 L2-hot loads per lane).
__device__ __forceinline__ float reduce_pmax(const float* __restrict__ pmax) {
    const int lane = threadIdx.x & 63;
    float m = 0.f;
#pragma unroll
    for (int t = 0; t < NPMAX / 64; ++t) m = fmaxf(m, pmax[lane + t * 64]);
#pragma unroll
    for (int k = 32; k >= 1; k >>= 1) m = fmaxf(m, __shfl_xor(m, k, 64));
    return m;
}

// ---------------------------------------------------------------------------
// absmax(A) -> 768 partial maxes, PLAIN stores (no atomic, no init needed).
// 768 blocks x 256 threads x 3 float4 = exactly NN*NN floats.
// ---------------------------------------------------------------------------
__global__ __launch_bounds__(256) void gud_absmax(const float* __restrict__ A,
                                                  float* __restrict__ pmax) {
    __shared__ float red[4];
    const float4* A4 = reinterpret_cast<const float4*>(A);
    const int base = blockIdx.x * 768 + threadIdx.x;
    float m = 0.f;
#pragma unroll
    for (int t = 0; t < 3; ++t) {
        float4 v = A4[base + t * 256];
        m = fmaxf(m, fmaxf(fmaxf(fabsf(v.x), fabsf(v.y)),
                           fmaxf(fabsf(v.z), fabsf(v.w))));
    }
#pragma unroll
    for (int k = 32; k >= 1; k >>= 1)
        m = fmaxf(m, __shfl_xor(m, k, 64));
    if ((threadIdx.x & 63) == 0) red[threadIdx.x >> 6] = m;
    __syncthreads();
    if (threadIdx.x == 0)
        pmax[blockIdx.x] = fmaxf(fmaxf(red[0], red[1]), fmaxf(red[2], red[3]));
}

// ---------------------------------------------------------------------------
// Fused quant (A -> i8 H/L, 15-bit fixed point) + prep (f16 QI/RJ).
// amax reduced wave-locally from the partial array.
// ---------------------------------------------------------------------------
__global__ __launch_bounds__(256) void gud_quantprep(
        const float* __restrict__ A,
        const float* __restrict__ pmax,
        unsigned char* __restrict__ qH,
        unsigned char* __restrict__ qL,
        const float* __restrict__ P,
        const float* __restrict__ W1,
        const float* __restrict__ b1,
        _Float16* __restrict__ QIh,
        _Float16* __restrict__ RJh) {
    const int b = blockIdx.x;
    if (b < NN * NN / 1024) {
        const float inv = 32639.0f / reduce_pmax(pmax);
        int gid = b * 256 + threadIdx.x;
        float4 v = reinterpret_cast<const float4*>(A)[gid];
        unsigned hw = 0, lw = 0;
        float elems[4] = {v.x, v.y, v.z, v.w};
#pragma unroll
        for (int e = 0; e < 4; ++e) {
            int q  = (int)rintf(fminf(fmaxf(elems[e] * inv, -32639.f), 32639.f));
            int hh = (q + 128) >> 8;           // floor((q+128)/256)
            int ll = q - (hh << 8);            // in [-128,127]
            hw |= ((unsigned)(hh & 0xff)) << (8 * e);
            lw |= ((unsigned)(ll & 0xff)) << (8 * e);
        }
        reinterpret_cast<unsigned*>(qH)[gid] = hw;
        reinterpret_cast<unsigned*>(qL)[gid] = lw;
    } else {
        int gid = (b - NN * NN / 1024) * 256 + threadIdx.x;   // 0 .. NN*64-1
        int i  = gid >> 6;
        int lf = gid & 63;
        int l  = (lf >> 5) + 1;   // 1 or 2
        int f  = lf & 31;
        const float* prow = P + i * FDIM;
        const float* wp   = W1 + l * FDIM * FDIM + f;
        float q = 0.f;
#pragma unroll
        for (int c = 0; c < FDIM; ++c) q = fmaf(prow[c], wp[c * FDIM], q);
        QIh[i * 64 + lf] = (_Float16)(q + b1[l * FDIM + f]);
        RJh[i * 64 + lf] = (_Float16)(-q);
    }
}

// ---------------------------------------------------------------------------
// Fused i8 GEMM + conv (r16 structure + T5 setprio around MFMA cluster).
// 8 waves = (kh, wr, wc); 3 lexical LDS buffers, fully unrolled 12-step
// K-loop with counted vmcnt(6); kh=1 a2 exchanged via LDS; kh=0 waves run
// the f16 conv epilogue.
// ---------------------------------------------------------------------------
__global__ __launch_bounds__(512, 1) void gud_fused(
        const unsigned char* __restrict__ qH,
        const unsigned char* __restrict__ qL,
        const float* __restrict__ pmax,
        const float* __restrict__ A,
        const _Float16* __restrict__ QIh,
        const _Float16* __restrict__ RJh,
        const float* __restrict__ b1,
        const float* __restrict__ W2,
        const float* __restrict__ b2,
        float* __restrict__ out) {
    __shared__ alignas(16) char sb0[49152];
    __shared__ alignas(16) char sb1[49152];
    __shared__ alignas(16) char sb2[49152];

    const int tid  = threadIdx.x;
    const int lane = tid & 63;
    const int w    = tid >> 6;          // wave 0..7
    const int kh   = w >> 2;            // K-half
    const int sub  = w & 3;             // 0=H@i0, 1=L@i0, 2=H@j0, 3=L@j0
    const int wr   = sub >> 1, wc = sub & 1;

    // XCD-chunked swizzle over the 256-block grid (256 % 8 == 0)
    const int lin = blockIdx.x;
    const int swz = (lin & 7) * 32 + (lin >> 3);
    const int by  = swz >> 4, bx = swz & 15;
    const int i0  = by * TG, j0 = bx * TG;

    // ---- staging: wave w owns subtile (kh, sub) of each buffer
    const unsigned char* src = (sub & 1) ? qL : qH;
    const int rowbase = (sub < 2) ? i0 : j0;
    const int khbyte  = kh * (NN / 2);  // kh * 768 cols * 1 B
    int goffs[6];
#pragma unroll
    for (int s = 0; s < 6; ++s) {
        int rt    = 16 * s + (lane >> 2);          // row within tile 0..95
        int chunk = (lane & 3) ^ ((rt >> 1) & 3);  // inverse swizzle on source
        goffs[s]  = (rowbase + rt) * NN + khbyte + chunk * 16;
    }

    // ---- fragment read offsets (within this half's region of a buffer)
    const int hbase = kh * 24576;
    int aoff[3], boff[3];
    const int kb = lane >> 4;
#pragma unroll
    for (int m = 0; m < 3; ++m) {
        int ra  = wr * 48 + m * 16 + (lane & 15);
        aoff[m] = hbase + ra * 64 + ((kb ^ ((ra >> 1) & 3)) * 16);
        int rb  = wc * 48 + m * 16 + (lane & 15);
        boff[m] = hbase + 12288 + rb * 64 + ((kb ^ ((rb >> 1) & 3)) * 16);
    }

    i32x4 accH[3][3], accX[3][3];
#pragma unroll
    for (int m = 0; m < 3; ++m)
#pragma unroll
        for (int n = 0; n < 3; ++n) {
            accH[m][n] = (i32x4){0, 0, 0, 0};
            accX[m][n] = (i32x4){0, 0, 0, 0};
        }

    auto compute = [&](const char (&buf)[49152]) {
        i32x4 hA[3], lA[3], hB[3], lB[3];
#pragma unroll
        for (int m = 0; m < 3; ++m) {
            hA[m] = *(const i32x4*)(&buf[aoff[m]]);
            lA[m] = *(const i32x4*)(&buf[aoff[m] + 6144]);
            hB[m] = *(const i32x4*)(&buf[boff[m]]);
            lB[m] = *(const i32x4*)(&buf[boff[m] + 6144]);
        }
        __builtin_amdgcn_s_setprio(1);
#pragma unroll
        for (int m = 0; m < 3; ++m)
#pragma unroll
            for (int n = 0; n < 3; ++n) {
                accH[m][n] = __builtin_amdgcn_mfma_i32_16x16x64_i8(hA[m], hB[n], accH[m][n], 0, 0, 0);
                accX[m][n] = __builtin_amdgcn_mfma_i32_16x16x64_i8(hA[m], lB[n], accX[m][n], 0, 0, 0);
                accX[m][n] = __builtin_amdgcn_mfma_i32_16x16x64_i8(lA[m], hB[n], accX[m][n], 0, 0, 0);
            }
        __builtin_amdgcn_s_setprio(0);
    };

    // ---- prologue: stage tile 0 -> sb0, tile 1 -> sb1
#pragma unroll
    for (int s = 0; s < 6; ++s)
        gload_lds16((const char*)src + goffs[s], sb0 + w * 6144 + s * 1024);
#pragma unroll
    for (int s = 0; s < 6; ++s)
        gload_lds16((const char*)src + goffs[s] + KS, sb1 + w * 6144 + s * 1024);

    // ---- fully unrolled main loop: static buffer names, counted vmcnt.
#define GSTEP(BC, BS, KT, VC) do {                                           \
    asm volatile("s_waitcnt vmcnt(" #VC ")" ::: "memory");                   \
    __builtin_amdgcn_s_barrier();                                            \
    if ((KT) < NTH) {                                                        \
        _Pragma("unroll")                                                    \
        for (int s = 0; s < 6; ++s)                                          \
            gload_lds16((const char*)src + goffs[s] + (KT) * KS,             \
                        BS + w * 6144 + s * 1024);                           \
    }                                                                        \
    compute(BC);                                                             \
} while (0)

    GSTEP(sb0, sb2, 2, 6);    // kt=0
    GSTEP(sb1, sb0, 3, 6);    // kt=1
    GSTEP(sb2, sb1, 4, 6);    // kt=2
    GSTEP(sb0, sb2, 5, 6);    // kt=3
    GSTEP(sb1, sb0, 6, 6);    // kt=4
    GSTEP(sb2, sb1, 7, 6);    // kt=5
    GSTEP(sb0, sb2, 8, 6);    // kt=6
    GSTEP(sb1, sb0, 9, 6);    // kt=7
    GSTEP(sb2, sb1, 10, 6);   // kt=8
    GSTEP(sb0, sb2, 11, 6);   // kt=9
    GSTEP(sb1, sb0, 12, 6);   // kt=10 (no stage)
    GSTEP(sb2, sb1, 13, 0);   // kt=11 (no stage, full drain)
#undef GSTEP

    // ---- dequant to f32 (accH/accX die here; frees VGPRs for epilogue)
    const float sq = reduce_pmax(pmax) / 32639.0f;
    const float c1 = sq * sq * 65536.0f;
    const float c2 = sq * sq * 256.0f;
    f32x4 af[3][3];
#pragma unroll
    for (int m = 0; m < 3; ++m)
#pragma unroll
        for (int n = 0; n < 3; ++n)
#pragma unroll
            for (int r = 0; r < 4; ++r)
                af[m][n][r] = c1 * (float)accH[m][n][r] + c2 * (float)accX[m][n][r];

    // ---- a2 exchange (kh=1 -> sb1) + QI/RJ staging (-> sb0)
    if (kh == 1) {
        char* pbase = sb1 + sub * 9216 + lane * 144;
#pragma unroll
        for (int m = 0; m < 3; ++m)
#pragma unroll
            for (int n = 0; n < 3; ++n)
                *(f32x4*)(pbase + (m * 3 + n) * 16) = af[m][n];
    }
    if (w < 4) {        // QI: 96 rows x 128 B -> sb0[0..12288)
#pragma unroll
        for (int sl = 0; sl < 3; ++sl) {
            int base = (w * 3 + sl) * 64;
            int idx  = base + lane;
            int c    = idx / 96;
            int row  = idx - c * 96;
            gload_lds16(QIh + (size_t)(i0 + row) * 64 + c * 8, sb0 + base * 16);
        }
    } else {            // RJ -> sb0[12288..24576)
#pragma unroll
        for (int sl = 0; sl < 3; ++sl) {
            int base = ((w - 4) * 3 + sl) * 64;
            int idx  = base + lane;
            int c    = idx / 96;
            int row  = idx - c * 96;
            gload_lds16(RJh + (size_t)(j0 + row) * 64 + c * 8, sb0 + 12288 + base * 16);
        }
    }

    // epilogue geometry + early A loads (kh=0 only; latency hides under sync)
    const int crow = (lane >> 4) * 4;
    const int ccol = lane & 15;
    int il[3], jl[3];
#pragma unroll
    for (int m = 0; m < 3; ++m) il[m] = wr * 48 + m * 16 + crow;
#pragma unroll
    for (int n = 0; n < 3; ++n) jl[n] = wc * 48 + n * 16 + ccol;

    float av[3][3][4];
    if (kh == 0) {
#pragma unroll
        for (int m = 0; m < 3; ++m)
#pragma unroll
            for (int n = 0; n < 3; ++n)
#pragma unroll
                for (int r = 0; r < 4; ++r)
                    av[m][n][r] = A[(size_t)(i0 + il[m] + r) * NN + j0 + jl[n]];
    }

    __syncthreads();    // drains vmcnt (QI/RJ, A) + lgkm (a2 ds_writes)

    if (kh == 1) return;

    // ---- add partner half's a2
    {
        const char* pbase = sb1 + sub * 9216 + lane * 144;
#pragma unroll
        for (int m = 0; m < 3; ++m)
#pragma unroll
            for (int n = 0; n < 3; ++n)
                af[m][n] += *(const f32x4*)(pbase + (m * 3 + n) * 16);
    }

    // ---- conv epilogue (f16 dot2, two-pass; r7/r13-verified)
    const char* QIl = sb0;
    const char* RJl = sb0 + 12288;

    float c0 = b2[0];
#pragma unroll
    for (int f = 0; f < FDIM; ++f) c0 = fmaf(fmaxf(b1[f], 0.f), W2[f], c0);
    const float bb1 = b2[1], bb2 = b2[2];

    h16x2 w2h[32];
#pragma unroll
    for (int k = 0; k < 32; ++k) {
        h16x2 t; t.x = (_Float16)W2[32 + 2 * k]; t.y = (_Float16)W2[33 + 2 * k];
        w2h[k] = t;
    }

    float mm[3][3][4];
    // pass 1: chunks 0..3 (features 0..31, layer 1) -> m1, fold into av
#pragma unroll
    for (int m = 0; m < 3; ++m)
#pragma unroll
        for (int n = 0; n < 3; ++n)
#pragma unroll
            for (int r = 0; r < 4; ++r) mm[m][n][r] = 0.f;
#pragma unroll
    for (int c = 0; c < 4; ++c) {
        uint4 rv[3];
#pragma unroll
        for (int n = 0; n < 3; ++n)
            rv[n] = *(const uint4*)(RJl + (c * 96 + jl[n]) * 16);
        uint4 qv[3][4];
#pragma unroll
        for (int m = 0; m < 3; ++m)
#pragma unroll
            for (int r = 0; r < 4; ++r)
                qv[m][r] = *(const uint4*)(QIl + (c * 96 + il[m] + r) * 16);
#pragma unroll
        for (int m = 0; m < 3; ++m)
#pragma unroll
            for (int n = 0; n < 3; ++n) {
                const unsigned* ru = (const unsigned*)&rv[n];
#pragma unroll
                for (int r = 0; r < 4; ++r) {
                    const unsigned* qu = (const unsigned*)&qv[m][r];
                    float acc_f = mm[m][n][r];
#pragma unroll
                    for (int e = 0; e < 4; ++e) {
                        h16x2 q = __builtin_bit_cast(h16x2, qu[e]);
                        h16x2 j = __builtin_bit_cast(h16x2, ru[e]);
                        h16x2 h = q + j;
                        h16x2 z = {(_Float16)0, (_Float16)0};
                        h = __builtin_elementwise_max(h, z);
                        acc_f = __builtin_amdgcn_fdot2(h, w2h[c * 4 + e], acc_f, false);
                    }
                    mm[m][n][r] = acc_f;
                }
            }
    }
#pragma unroll
    for (int m = 0; m < 3; ++m)
#pragma unroll
        for (int n = 0; n < 3; ++n)
#pragma unroll
            for (int r = 0; r < 4; ++r)
                av[m][n][r] *= (mm[m][n][r] + bb1);

    // pass 2: chunks 4..7 (features 32..63, layer 2) -> m2
#pragma unroll
    for (int m = 0; m < 3; ++m)
#pragma unroll
        for (int n = 0; n < 3; ++n)
#pragma unroll
            for (int r = 0; r < 4; ++r) mm[m][n][r] = 0.f;
#pragma unroll
    for (int c = 4; c < 8; ++c) {
        uint4 rv[3];
#pragma unroll
        for (int n = 0; n < 3; ++n)
            rv[n] = *(const uint4*)(RJl + (c * 96 + jl[n]) * 16);
        uint4 qv[3][4];
#pragma unroll
        for (int m = 0; m < 3; ++m)
#pragma unroll
            for (int r = 0; r < 4; ++r)
                qv[m][r] = *(const uint4*)(QIl + (c * 96 + il[m] + r) * 16);
#pragma unroll
        for (int m = 0; m < 3; ++m)
#pragma unroll
            for (int n = 0; n < 3; ++n) {
                const unsigned* ru = (const unsigned*)&rv[n];
#pragma unroll
                for (int r = 0; r < 4; ++r) {
                    const unsigned* qu = (const unsigned*)&qv[m][r];
                    float acc_f = mm[m][n][r];
#pragma unroll
                    for (int e = 0; e < 4; ++e) {
                        h16x2 q = __builtin_bit_cast(h16x2, qu[e]);
                        h16x2 j = __builtin_bit_cast(h16x2, ru[e]);
                        h16x2 h = q + j;
                        h16x2 z = {(_Float16)0, (_Float16)0};
                        h = __builtin_elementwise_max(h, z);
                        acc_f = __builtin_amdgcn_fdot2(h, w2h[c * 4 + e], acc_f, false);
                    }
                    mm[m][n][r] = acc_f;
                }
            }
    }

    // final: out = A*(m1+bb1) + A2*(m2+bb2) + diag(c0)
#pragma unroll
    for (int m = 0; m < 3; ++m)
#pragma unroll
        for (int n = 0; n < 3; ++n)
#pragma unroll
            for (int r = 0; r < 4; ++r) {
                float v = av[m][n][r] + af[m][n][r] * (mm[m][n][r] + bb2);
                int gi = i0 + il[m] + r;
                int gj = j0 + jl[n];
                if (gi == gj) v += c0;
                out[(size_t)gi * NN + gj] = v;
            }
}

// ---------------------------------------------------------------------------
extern "C" void kernel_launch(void* const* d_in, const int* in_sizes, int n_in,
                              void* d_out, int out_size, void* d_ws, size_t ws_size,
                              hipStream_t stream) {
    const float* A  = (const float*)d_in[0];   // [NN,NN] A_norm (symmetric)
    const float* P  = (const float*)d_in[1];   // [NN,32]
    const float* W1 = (const float*)d_in[2];   // [3,32,32]
    const float* b1 = (const float*)d_in[3];   // [3,32]
    const float* W2 = (const float*)d_in[4];   // [3,32,1]
    const float* b2 = (const float*)d_in[5];   // [3,1]
    float* out = (float*)d_out;

    unsigned char* qH = (unsigned char*)d_ws;                    // NN*NN i8
    unsigned char* qL = qH + (size_t)NN * NN;                    // NN*NN i8
    _Float16* QIh = (_Float16*)(qL + (size_t)NN * NN);           // NN*64 f16
    _Float16* RJh = QIh + (size_t)NN * 64;                       // NN*64 f16
    float* pmax = (float*)(RJh + (size_t)NN * 64);               // 768 f32

    gud_absmax<<<dim3(NPMAX), 256, 0, stream>>>(A, pmax);
    gud_quantprep<<<dim3(NN * NN / 1024 + NN * 64 / 256), 256, 0, stream>>>(
        A, pmax, qH, qL, P, W1, b1, QIh, RJh);
    gud_fused<<<dim3((NN / TG) * (NN / TG)), 512, 0, stream>>>(
        qH, qL, pmax, A, QIh, RJh, b1, W2, b2, out);
}